// Round 10
// baseline (187.221 us; speedup 1.0000x reference)
//
#include <hip/hip_runtime.h>
#include <hip/hip_bf16.h>

#define SEQ   2048
#define DM    1024
#define NH    16
#define DK    64
#define BATCH 2
#define M_TOT 4096
#define C1 0.18033688011112042f   // 0.125 * log2(e), folded into Q

typedef __attribute__((ext_vector_type(8))) short bf16x8;
typedef __attribute__((ext_vector_type(4))) float f32x4;
typedef __attribute__((ext_vector_type(16))) float f32x16;
typedef __attribute__((ext_vector_type(2))) int i32x2;
typedef unsigned short u16;

__device__ inline u16 f2b(float f) {               // f32 -> bf16 bits (RNE)
    union { float f; unsigned u; } x; x.f = f;
    return (u16)((x.u + 0x7FFFu + ((x.u >> 16) & 1u)) >> 16);
}

__device__ inline unsigned pk2(float a, float b) { // packed v_cvt_pk_bf16_f32
    __hip_bfloat162 h = __float22bfloat162_rn(make_float2(a, b));
    return *reinterpret_cast<unsigned*>(&h);
}

__device__ inline void async_cp16(const u16* g, u16* l) {
    __builtin_amdgcn_global_load_lds(
        (const __attribute__((address_space(1))) unsigned int*)g,
        (__attribute__((address_space(3))) unsigned int*)l, 16, 0, 0);
}

__device__ inline f32x16 zero16() {
    f32x16 z;
    #pragma unroll
    for (int i = 0; i < 16; ++i) z[i] = 0.f;
    return z;
}

__device__ inline bf16x8 mk8(unsigned a, unsigned b, unsigned c, unsigned d) {
    union { unsigned u[4]; bf16x8 v; } x;
    x.u[0] = a; x.u[1] = b; x.u[2] = c; x.u[3] = d;
    return x.v;
}

#define MFMA32(a, b, c) __builtin_amdgcn_mfma_f32_32x32x16_bf16(a, b, c, 0, 0, 0)

// ---------------------------------------------------------------------------
// prep: z<4 -> weight transpose+cast (W [k][n] f32 -> Wt [n][k] bf16);
//       z>=4 -> x f32 -> bf16 cast (fused to save a launch gap).
// ---------------------------------------------------------------------------
__global__ __launch_bounds__(256) void prep(
    const float* __restrict__ x, uint2* __restrict__ xb,
    const float* __restrict__ W0, const float* __restrict__ W1,
    const float* __restrict__ W2, const float* __restrict__ W3,
    u16* __restrict__ WtBase)
{
    __shared__ float tile[32][33];
    const int t = threadIdx.x, z = blockIdx.z;
    if (z >= 4) {
        int bid = ((z - 4) << 10) + (blockIdx.y << 5) + blockIdx.x;
        int gid = bid * 256 + t;
        float4 v = ((const float4*)x)[gid];
        uint2 o;
        o.x = pk2(v.x, v.y); o.y = pk2(v.z, v.w);
        xb[gid] = o;
        return;
    }
    const int n0 = blockIdx.x << 5, k0 = blockIdx.y << 5;
    const float* W = (z == 0) ? W0 : (z == 1) ? W1 : (z == 2) ? W2 : W3;
    u16* Wt = WtBase + (size_t)z * DM * DM;
    #pragma unroll
    for (int i = 0; i < 4; ++i) {
        int idx = t + (i << 8); int r = idx >> 5, c = idx & 31;
        tile[r][c] = W[(size_t)(k0 + r) * DM + n0 + c];
    }
    __syncthreads();
    #pragma unroll
    for (int i = 0; i < 4; ++i) {
        int idx = t + (i << 8); int r = idx >> 5, c = idx & 31;
        Wt[(size_t)(n0 + r) * DM + k0 + c] = f2b(tile[c][r]);
    }
}

// ---------------------------------------------------------------------------
// MFMA GEMM (QKV):  C = A @ Bt^T + bias.  128x128 tile, BK=32, 2-phase double
// buffered main loop (R6-verified).
// ---------------------------------------------------------------------------
__global__ __launch_bounds__(256) void gemm_bt(
    const u16* __restrict__ A, const u16* __restrict__ Bt, int mode,
    const float* __restrict__ bias0, const float* __restrict__ bias1,
    const float* __restrict__ bias2,
    void* __restrict__ out0, void* __restrict__ out1, void* __restrict__ out2)
{
    __shared__ u16 sh[16896];            // As[2][4096] | Bs[2][4096] | slack
    u16* As = sh;                        // + buf*4096
    u16* Bs = sh + 8192;                 // + buf*4096
    const int t = threadIdx.x, wid = t >> 6, lane = t & 63;
    const int lr = lane & 15, quad = lane >> 4;
    const int m0 = blockIdx.y << 7, n0 = blockIdx.x << 7;
    const int wm = (wid & 1) << 6, wn = (wid >> 1) << 6;
    const int rowA = lane >> 2;
    const int colA = (((lane & 3) - ((lane >> 3) & 3)) & 3) << 3;  // swizzled src
    const int sA = (((lr >> 1) + quad) & 3) << 3;                  // read slot

    f32x4 acc[4][4];
    #pragma unroll
    for (int i = 0; i < 4; ++i)
        #pragma unroll
        for (int j = 0; j < 4; ++j) acc[i][j] = (f32x4){0.f, 0.f, 0.f, 0.f};

    auto stage = [&](int k0s, int buf) {
        #pragma unroll
        for (int i = 0; i < 2; ++i) {
            int ch = wid * 2 + i;
            async_cp16(A  + (size_t)(m0 + ch * 16 + rowA) * DM + k0s + colA,
                       As + buf * 4096 + ch * 16 * 32);
            async_cp16(Bt + (size_t)(n0 + ch * 16 + rowA) * DM + k0s + colA,
                       Bs + buf * 4096 + ch * 16 * 32);
        }
    };

    stage(0, 0);
    __syncthreads();

    for (int k0 = 0; k0 < DM; k0 += 32) {
        const int cur = (k0 >> 5) & 1;
        if (k0 + 32 < DM) stage(k0 + 32, cur ^ 1);

        const u16* Ac = As + cur * 4096;
        const u16* Bc = Bs + cur * 4096;
        bf16x8 af[4], bfr[4];
        #pragma unroll
        for (int mt = 0; mt < 4; ++mt)
            af[mt] = *(const bf16x8*)(Ac + (wm + 16 * mt + lr) * 32 + sA);
        #pragma unroll
        for (int nt = 0; nt < 4; ++nt)
            bfr[nt] = *(const bf16x8*)(Bc + (wn + 16 * nt + lr) * 32 + sA);
        #pragma unroll
        for (int mt = 0; mt < 4; ++mt)
            #pragma unroll
            for (int nt = 0; nt < 4; ++nt)
                acc[mt][nt] = __builtin_amdgcn_mfma_f32_16x16x32_bf16(
                    af[mt], bfr[nt], acc[mt][nt], 0, 0, 0);
        __syncthreads();
    }

    {
        u16* wstrip = sh + wid * 1152;
        const int ngb = n0 + wn;
        const int which = ngb >> 10, nnb = ngb & 1023;
        const int h = nnb >> 6;
        const float* bp = (which == 0) ? bias0 : (which == 1) ? bias1 : bias2;
        const float sc = (which == 0) ? C1 : 1.0f;
        float bias_v[4];
        #pragma unroll
        for (int nt = 0; nt < 4; ++nt) bias_v[nt] = bp[nnb + 16 * nt + lr];

        if (which != 1) {
            // Q (*C1) and V: transposed output [bh][d][s], packed epilogue
            u16* dst = (which == 0) ? (u16*)out0 : (u16*)out2;
            #pragma unroll
            for (int mt = 0; mt < 4; ++mt) {
                #pragma unroll
                for (int nt = 0; nt < 4; ++nt) {
                    uint2 w;
                    w.x = pk2((acc[mt][nt][0] + bias_v[nt]) * sc,
                              (acc[mt][nt][1] + bias_v[nt]) * sc);
                    w.y = pk2((acc[mt][nt][2] + bias_v[nt]) * sc,
                              (acc[mt][nt][3] + bias_v[nt]) * sc);
                    *(uint2*)(wstrip + (16 * nt + lr) * 16 + quad * 4) = w;
                }
                asm volatile("s_waitcnt lgkmcnt(0)" ::: "memory");
                #pragma unroll
                for (int half = 0; half < 2; ++half) {
                    int id = lane + 64 * half;
                    int d = id >> 1, cho = (id & 1) << 3;
                    int m = m0 + wm + 16 * mt + cho;
                    int b = m >> 11, s = m & (SEQ - 1);
                    *(uint4*)(dst + ((size_t)(b * NH + h) * DK + d) * SEQ + s) =
                        *(const uint4*)(wstrip + d * 16 + cho);
                }
                asm volatile("s_waitcnt lgkmcnt(0)" ::: "memory");
            }
        } else {
            // K: [bh][s][d], strip-transpose epilogue
            u16* dst = (u16*)out1;
            #pragma unroll
            for (int mt = 0; mt < 4; ++mt) {
                #pragma unroll
                for (int nt = 0; nt < 4; ++nt)
                    #pragma unroll
                    for (int r = 0; r < 4; ++r)
                        wstrip[(quad * 4 + r) * 72 + 16 * nt + lr] =
                            f2b(acc[mt][nt][r] + bias_v[nt]);
                asm volatile("s_waitcnt lgkmcnt(0)" ::: "memory");
                #pragma unroll
                for (int half = 0; half < 2; ++half) {
                    int id = lane + 64 * half;
                    int mloc = id >> 3, dl = (id & 7) << 3;
                    int m = m0 + wm + 16 * mt + mloc;
                    int b = m >> 11, s = m & (SEQ - 1);
                    *(uint4*)(dst + ((size_t)(b * NH + h) * SEQ + s) * DK + dl) =
                        *(const uint4*)(wstrip + mloc * 72 + dl);
                }
                asm volatile("s_waitcnt lgkmcnt(0)" ::: "memory");
            }
        }
    }
}

// ---------------------------------------------------------------------------
// Final GEMM:  O[4096][1024] f32 = A @ Bt^T + bias.  64x128 tile -> 512
// blocks = 2 blocks/CU.  2-phase loop; 4 waves each own 64x32 (acc[4][2]).
// ---------------------------------------------------------------------------
__global__ __launch_bounds__(256) void gemm_o(
    const u16* __restrict__ A, const u16* __restrict__ Bt,
    const float* __restrict__ bias, float* __restrict__ O)
{
    __shared__ u16 sh[12288];            // As[2][2048] | Bs[2][4096]
    u16* As = sh;                        // + buf*2048
    u16* Bs = sh + 4096;                 // + buf*4096
    const int t = threadIdx.x, wid = t >> 6, lane = t & 63;
    const int lr = lane & 15, quad = lane >> 4;
    const int m0 = blockIdx.y << 6, n0 = blockIdx.x << 7;
    const int wn = wid << 5;
    const int rowA = lane >> 2;
    const int colA = (((lane & 3) - ((lane >> 3) & 3)) & 3) << 3;
    const int sA = (((lr >> 1) + quad) & 3) << 3;

    f32x4 acc[4][2];
    #pragma unroll
    for (int i = 0; i < 4; ++i)
        #pragma unroll
        for (int j = 0; j < 2; ++j) acc[i][j] = (f32x4){0.f, 0.f, 0.f, 0.f};

    auto stage = [&](int k0s, int buf) {
        async_cp16(A + (size_t)(m0 + wid * 16 + rowA) * DM + k0s + colA,
                   As + buf * 2048 + wid * 512);
        async_cp16(Bt + (size_t)(n0 + (2 * wid) * 16 + rowA) * DM + k0s + colA,
                   Bs + buf * 4096 + (2 * wid) * 512);
        async_cp16(Bt + (size_t)(n0 + (2 * wid + 1) * 16 + rowA) * DM + k0s + colA,
                   Bs + buf * 4096 + (2 * wid + 1) * 512);
    };

    stage(0, 0);
    __syncthreads();

    for (int k0 = 0; k0 < DM; k0 += 32) {
        const int cur = (k0 >> 5) & 1;
        if (k0 + 32 < DM) stage(k0 + 32, cur ^ 1);

        const u16* Ac = As + cur * 2048;
        const u16* Bc = Bs + cur * 4096;
        bf16x8 af[4], bfr[2];
        #pragma unroll
        for (int mt = 0; mt < 4; ++mt)
            af[mt] = *(const bf16x8*)(Ac + (16 * mt + lr) * 32 + sA);
        #pragma unroll
        for (int nt = 0; nt < 2; ++nt)
            bfr[nt] = *(const bf16x8*)(Bc + (wn + 16 * nt + lr) * 32 + sA);
        #pragma unroll
        for (int mt = 0; mt < 4; ++mt)
            #pragma unroll
            for (int nt = 0; nt < 2; ++nt)
                acc[mt][nt] = __builtin_amdgcn_mfma_f32_16x16x32_bf16(
                    af[mt], bfr[nt], acc[mt][nt], 0, 0, 0);
        __syncthreads();
    }

    // f32 epilogue via per-wave [16][36] strip -> coalesced float4 stores
    float bias_v[2];
    #pragma unroll
    for (int nt = 0; nt < 2; ++nt) bias_v[nt] = bias[n0 + wn + 16 * nt + lr];
    float* strip = (float*)sh + wid * 576;       // 2304 B per wave
    #pragma unroll
    for (int mt = 0; mt < 4; ++mt) {
        #pragma unroll
        for (int nt = 0; nt < 2; ++nt)
            #pragma unroll
            for (int r = 0; r < 4; ++r)
                strip[(quad * 4 + r) * 36 + 16 * nt + lr] =
                    acc[mt][nt][r] + bias_v[nt];
        asm volatile("s_waitcnt lgkmcnt(0)" ::: "memory");
        #pragma unroll
        for (int rr = 0; rr < 2; ++rr) {
            int id = lane + 64 * rr;
            int row = id >> 3, ch = id & 7;
            float4 v = *(const float4*)(strip + row * 36 + ch * 4);
            *(float4*)(O + (size_t)(m0 + 16 * mt + row) * DM
                         + n0 + wn + ch * 4) = v;
        }
        asm volatile("s_waitcnt lgkmcnt(0)" ::: "memory");
    }
}

// ---------------------------------------------------------------------------
// Flash attention v13 = v10 (HW-verified 49.7us) with per-iter overhead trim:
//  - kv loop unrolled x2: buffer parity compile-time -> LDS bases hoisted
//    out of the loop (base reg + offset: immediates), DMA dests constant.
//  - running global staging pointers (4 ptrs, advanced +16KB K / +256B V per
//    staged pair) replace per-iter address rebuild (~80 VALU -> 8).
//  - hoisted zero C-operand Z (kills 32 v_mov/iter).
//  - PV(kvt) interleaved right after softmax(kvt): same accumulate order per
//    O register (numerics identical), MFMA pipe busy during softmax VALU.
// Structure/occupancy unchanged: 512 thr / 8 waves (4 q x 2 kv-groups),
// 128 q rows, K/V double-buffered, 1 barrier/iter, NO min-waves bound
// (R7/R8 lesson: forcing >4 waves/SIMD spills; ~128 unified V+AGPR/wave).
// LDS 66560 B -> 2 blocks/CU.
//   Qt (C1-scaled): [bh][d][s]; K: [bh][s][d]; Vt: [bh][64][s] bf16.
// ---------------------------------------------------------------------------
__global__ __launch_bounds__(512) void attn_mfma(
    const u16* __restrict__ Qt, const u16* __restrict__ K,
    const u16* __restrict__ Vt, u16* __restrict__ A)
{
    __shared__ u16 sh[33280];

    const int t = threadIdx.x, wid = t >> 6, lane = t & 63;
    const int l31 = lane & 31, hi = lane >> 5, l7 = lane & 7;
    const int g = wid >> 2, wq = wid & 3;
    const int bx = blockIdx.x;
    const int xcd = bx & 7, within = bx >> 3;      // 0..63
    const int bh  = xcd * 4 + (within >> 4);       // 4 bh per XCD (L2 affinity)
    const int q0  = (within & 15) << 7;            // 128 q rows per block

    const u16* Kb = K  + (size_t)bh * SEQ * DK;
    const u16* Vb = Vt + (size_t)bh * DK * SEQ;

    // Q B-fragments: bQ[s][j] = Qt[d = 16s + 8hi + j][q0 + 32*wq + l31]
    const int qw = q0 + 32 * wq + l31;
    const u16* Qb = Qt + (size_t)bh * DK * SEQ + qw;
    bf16x8 bQ[4];
    #pragma unroll
    for (int s = 0; s < 4; ++s)
        #pragma unroll
        for (int j = 0; j < 8; ++j)
            bQ[s][j] = (short)Qb[(size_t)(16 * s + 8 * hi + j) * SEQ];

    f32x16 O0 = zero16(), O1 = zero16();
    const f32x16 Z = zero16();                     // hoisted zero C-operand
    float lr = 0.f;

    // staging: wave w stages rows w*8 + (lane>>3); source chunk XOR-swizzled
    // so LDS[row][ck] = G[row][ck ^ (row&7)].
    const int w8row = wid * 8 + (lane >> 3);       // 0..63
    const int scol  = ((l7 ^ (lane >> 3)) << 3);   // row&7 == lane>>3

    const int rA = l31 * 64;                       // row base (u16)
    int cks[4];
    #pragma unroll
    for (int s = 0; s < 4; ++s) cks[s] = ((2 * s + hi) ^ l7) << 3;

    // hoisted LDS bases (buf1 = +8192 u16)
    const u16* kb0 = sh + (g << 12) + rA;
    const u16* vb0 = sh + 16384 + (g << 12) + rA;
    u16* kd0 = sh + wid * 512;
    u16* kd1 = kd0 + 8192;
    u16* vd0 = sh + 16384 + wid * 512;
    u16* vd1 = vd0 + 8192;

    // running global staging pointers (advance per staged 128-kv pair)
    const u16* kg0 = Kb + (size_t)w8row * DK + scol;
    const u16* kg1 = Kb + (size_t)(64 + w8row) * DK + scol;
    const u16* vg0 = Vb + (size_t)w8row * SEQ + scol;
    const u16* vg1 = vg0 + 64;

    auto stage_to = [&](u16* kd, u16* vd) {
        async_cp16(kg0, kd);
        async_cp16(kg1, kd + 4096);
        async_cp16(vg0, vd);
        async_cp16(vg1, vd + 4096);
        kg0 += 128 * DK; kg1 += 128 * DK; vg0 += 128; vg1 += 128;
    };

    // softmax(kvt) + immediate PV(kvt): c0/c1 are this kvt's V column slots
    auto smax_pv = [&](const f32x16& S, const u16* vbp, int c0, int c1) {
        float e[16];
        #pragma unroll
        for (int r = 0; r < 16; ++r)
            e[r] = __builtin_amdgcn_exp2f(S[r]);
        lr += (((e[0] + e[1]) + (e[2] + e[3])) +
               ((e[4] + e[5]) + (e[6] + e[7]))) +
              (((e[8] + e[9]) + (e[10] + e[11])) +
               ((e[12] + e[13]) + (e[14] + e[15])));
        unsigned pk8[8];
        #pragma unroll
        for (int i = 0; i < 8; ++i) pk8[i] = pk2(e[2 * i], e[2 * i + 1]);
        i32x2 r0 = __builtin_amdgcn_permlane32_swap(
            (int)pk8[0], (int)pk8[2], false, false);
        i32x2 r1 = __builtin_amdgcn_permlane32_swap(
            (int)pk8[1], (int)pk8[3], false, false);
        i32x2 r2 = __builtin_amdgcn_permlane32_swap(
            (int)pk8[4], (int)pk8[6], false, false);
        i32x2 r3 = __builtin_amdgcn_permlane32_swap(
            (int)pk8[5], (int)pk8[7], false, false);
        bf16x8 pw0 = mk8((unsigned)r0[0], (unsigned)r1[0],
                         (unsigned)r0[1], (unsigned)r1[1]);
        bf16x8 pw1 = mk8((unsigned)r2[0], (unsigned)r3[0],
                         (unsigned)r2[1], (unsigned)r3[1]);
        __builtin_amdgcn_s_setprio(1);
        bf16x8 va = *(const bf16x8*)(vbp + c0);
        bf16x8 vb = *(const bf16x8*)(vbp + 2048 + c0);
        O0 = MFMA32(pw0, va, O0);
        O1 = MFMA32(pw0, vb, O1);
        va = *(const bf16x8*)(vbp + c1);
        vb = *(const bf16x8*)(vbp + 2048 + c1);
        O0 = MFMA32(pw1, va, O0);
        O1 = MFMA32(pw1, vb, O1);
        __builtin_amdgcn_s_setprio(0);
    };

    auto body = [&](const u16* kbp, const u16* vbp) {
        f32x16 Sv0, Sv1;
        __builtin_amdgcn_s_setprio(1);
        {
            bf16x8 a;
            a = *(const bf16x8*)(kbp + cks[0]);        Sv0 = MFMA32(a, bQ[0], Z);
            a = *(const bf16x8*)(kbp + cks[1]);        Sv0 = MFMA32(a, bQ[1], Sv0);
            a = *(const bf16x8*)(kbp + cks[2]);        Sv0 = MFMA32(a, bQ[2], Sv0);
            a = *(const bf16x8*)(kbp + cks[3]);        Sv0 = MFMA32(a, bQ[3], Sv0);
            a = *(const bf16x8*)(kbp + 2048 + cks[0]); Sv1 = MFMA32(a, bQ[0], Z);
            a = *(const bf16x8*)(kbp + 2048 + cks[1]); Sv1 = MFMA32(a, bQ[1], Sv1);
            a = *(const bf16x8*)(kbp + 2048 + cks[2]); Sv1 = MFMA32(a, bQ[2], Sv1);
            a = *(const bf16x8*)(kbp + 2048 + cks[3]); Sv1 = MFMA32(a, bQ[3], Sv1);
        }
        __builtin_amdgcn_s_setprio(0);
        smax_pv(Sv0, vbp, cks[0], cks[1]);   // kvt=0 -> w=0,1
        smax_pv(Sv1, vbp, cks[2], cks[3]);   // kvt=1 -> w=2,3
    };

    stage_to(kd0, vd0);                        // tile pair 0 -> buf0
    __syncthreads();

    #pragma unroll 1
    for (int s2 = 0; s2 < 8; ++s2) {
        // even sub-iter: stage pair (2*s2+1) -> buf1, compute buf0
        stage_to(kd1, vd1);
        body(kb0, vb0);
        __syncthreads();
        // odd sub-iter: stage pair (2*s2+2) -> buf0 (guarded), compute buf1
        if (s2 < 7) stage_to(kd0, vd0);
        body(kb0 + 8192, vb0 + 8192);
        __syncthreads();
    }

    // fold lane<->lane+32 (each holds half the kv rows for q=l31)
    lr += __shfl_xor(lr, 32);

    // cross-group reduction: group 1 dumps (O,l) into the retired K region.
    float* lred = (float*)(sh + 32768);
    if (g == 1) {
        float* red = (float*)sh + wq * 2048;       // 8KB per q-wave
        #pragma unroll
        for (int c = 0; c < 4; ++c) {
            float4 v0 = make_float4(O0[4*c], O0[4*c+1], O0[4*c+2], O0[4*c+3]);
            float4 v1 = make_float4(O1[4*c], O1[4*c+1], O1[4*c+2], O1[4*c+3]);
            *(float4*)(red + lane * 32 + ((c ^ l7) << 2))       = v0;
            *(float4*)(red + lane * 32 + (((c + 4) ^ l7) << 2)) = v1;
        }
        if (hi == 0) lred[wq * 32 + l31] = lr;
    }
    __syncthreads();

    if (g == 0) {
        float* red = (float*)sh + wq * 2048;
        #pragma unroll
        for (int c = 0; c < 4; ++c) {
            float4 v0 = *(const float4*)(red + lane * 32 + ((c ^ l7) << 2));
            float4 v1 = *(const float4*)(red + lane * 32 + (((c + 4) ^ l7) << 2));
            O0[4*c] += v0.x; O0[4*c+1] += v0.y; O0[4*c+2] += v0.z; O0[4*c+3] += v0.w;
            O1[4*c] += v1.x; O1[4*c+1] += v1.y; O1[4*c+2] += v1.z; O1[4*c+3] += v1.w;
        }
        lr += lred[wq * 32 + l31];

        // broadcast denominators across the wave's 32 q via per-wave LDS table
        float* lt = (float*)(sh + 33024) + wq * 32;
        lt[l31] = lr;
        asm volatile("s_waitcnt lgkmcnt(0)" ::: "memory");

        const int b = bh >> 4, h = bh & 15;
        u16* Ab = A + (size_t)b * SEQ * DM + h * DK + l31;
        #pragma unroll
        for (int r = 0; r < 16; ++r) {
            const int qr = (r & 3) + 8 * (r >> 2) + 4 * hi;
            const float inv = 1.f / lt[qr];
            u16* dst = Ab + (size_t)(q0 + 32 * wq + qr) * DM;
            dst[0]  = f2b(O0[r] * inv);
            dst[32] = f2b(O1[r] * inv);
        }
    }
}

// ---------------------------------------------------------------------------
extern "C" void kernel_launch(void* const* d_in, const int* in_sizes, int n_in,
                              void* d_out, int out_size, void* d_ws, size_t ws_size,
                              hipStream_t stream)
{
    const float* x  = (const float*)d_in[0];
    const float* Wq = (const float*)d_in[1];
    const float* bq = (const float*)d_in[2];
    const float* Wk = (const float*)d_in[3];
    const float* bk = (const float*)d_in[4];
    const float* Wv = (const float*)d_in[5];
    const float* bv = (const float*)d_in[6];
    const float* Wo = (const float*)d_in[7];
    const float* bo = (const float*)d_in[8];

    const size_t NE = (size_t)M_TOT * DM;        // 4M elems
    u16* xb     = (u16*)d_ws;                    //  8 MB  x bf16
    u16* wt_qkv = xb + NE;                       //  6 MB  [3][1024][1024] (n,k)
    u16* wt_o   = wt_qkv + 3 * (size_t)DM * DM;  //  2 MB
    u16* qt_ws  = wt_o + (size_t)DM * DM;        //  8 MB  [bh][d][s] (C1-scaled)
    u16* k_ws   = qt_ws + NE;                    //  8 MB  [bh][s][d]
    u16* vt_ws  = k_ws + NE;                     //  8 MB  [bh][d][s]
    u16* a_ws   = vt_ws + NE;                    //  8 MB  [4096][1024]

    prep<<<dim3(32, 32, 8), 256, 0, stream>>>(
        x, (uint2*)xb, Wq, Wk, Wv, Wo, wt_qkv);

    gemm_bt<<<dim3(24, 32), 256, 0, stream>>>(
        xb, wt_qkv, 1, bq, bk, bv, qt_ws, k_ws, vt_ws);

    attn_mfma<<<dim3(512), 512, 0, stream>>>(qt_ws, k_ws, vt_ws, a_ws);

    gemm_o<<<dim3(8, 64), 256, 0, stream>>>(a_ws, wt_o, bo, (float*)d_out);
}

// Round 12
// 183.011 us; speedup vs baseline: 1.0230x; 1.0230x over previous
//
#include <hip/hip_runtime.h>
#include <hip/hip_bf16.h>

#define SEQ   2048
#define DM    1024
#define NH    16
#define DK    64
#define BATCH 2
#define M_TOT 4096
#define C1 0.18033688011112042f   // 0.125 * log2(e), folded into Q

typedef __attribute__((ext_vector_type(8))) short bf16x8;
typedef __attribute__((ext_vector_type(4))) float f32x4;
typedef __attribute__((ext_vector_type(16))) float f32x16;
typedef __attribute__((ext_vector_type(2))) int i32x2;
typedef unsigned short u16;

__device__ inline u16 f2b(float f) {               // f32 -> bf16 bits (RNE)
    union { float f; unsigned u; } x; x.f = f;
    return (u16)((x.u + 0x7FFFu + ((x.u >> 16) & 1u)) >> 16);
}

__device__ inline unsigned pk2(float a, float b) { // packed v_cvt_pk_bf16_f32
    __hip_bfloat162 h = __float22bfloat162_rn(make_float2(a, b));
    return *reinterpret_cast<unsigned*>(&h);
}

__device__ inline void async_cp16(const u16* g, u16* l) {
    __builtin_amdgcn_global_load_lds(
        (const __attribute__((address_space(1))) unsigned int*)g,
        (__attribute__((address_space(3))) unsigned int*)l, 16, 0, 0);
}

__device__ inline f32x16 zero16() {
    f32x16 z;
    #pragma unroll
    for (int i = 0; i < 16; ++i) z[i] = 0.f;
    return z;
}

__device__ inline bf16x8 mk8(unsigned a, unsigned b, unsigned c, unsigned d) {
    union { unsigned u[4]; bf16x8 v; } x;
    x.u[0] = a; x.u[1] = b; x.u[2] = c; x.u[3] = d;
    return x.v;
}

#define MFMA32(a, b, c) __builtin_amdgcn_mfma_f32_32x32x16_bf16(a, b, c, 0, 0, 0)

// ---------------------------------------------------------------------------
// prep: z<4 -> weight transpose+cast (W [k][n] f32 -> Wt [n][k] bf16),
//             stores vectorized: 2 adjacent k-columns packed per uint store.
//             Tile-read banks (2*c2+r)%32 -> 2-way aliasing = free (m136).
//       z>=4 -> x f32 -> bf16 cast (fused to save a launch gap).
// ---------------------------------------------------------------------------
__global__ __launch_bounds__(256) void prep(
    const float* __restrict__ x, uint2* __restrict__ xb,
    const float* __restrict__ W0, const float* __restrict__ W1,
    const float* __restrict__ W2, const float* __restrict__ W3,
    u16* __restrict__ WtBase)
{
    __shared__ float tile[32][33];
    const int t = threadIdx.x, z = blockIdx.z;
    if (z >= 4) {
        int bid = ((z - 4) << 10) + (blockIdx.y << 5) + blockIdx.x;
        int gid = bid * 256 + t;
        float4 v = ((const float4*)x)[gid];
        uint2 o;
        o.x = pk2(v.x, v.y); o.y = pk2(v.z, v.w);
        xb[gid] = o;
        return;
    }
    const int n0 = blockIdx.x << 5, k0 = blockIdx.y << 5;
    const float* W = (z == 0) ? W0 : (z == 1) ? W1 : (z == 2) ? W2 : W3;
    u16* Wt = WtBase + (size_t)z * DM * DM;
    #pragma unroll
    for (int i = 0; i < 4; ++i) {
        int idx = t + (i << 8); int r = idx >> 5, c = idx & 31;
        tile[r][c] = W[(size_t)(k0 + r) * DM + n0 + c];
    }
    __syncthreads();
    #pragma unroll
    for (int i = 0; i < 2; ++i) {
        int idx = t + (i << 8);                  // 512 uint stores per tile
        int r = idx >> 4, c2 = idx & 15;         // row n0+r, k-pair k0+2*c2
        unsigned w = pk2(tile[2 * c2][r], tile[2 * c2 + 1][r]);
        *(unsigned*)(Wt + (size_t)(n0 + r) * DM + k0 + 2 * c2) = w;
    }
}

// ---------------------------------------------------------------------------
// MFMA GEMM (QKV):  C = A @ Bt^T + bias.  128x128 tile, BK=32, 2-phase double
// buffered main loop (R6-verified).  768 blocks = exactly 3 blocks/CU.
// ---------------------------------------------------------------------------
__global__ __launch_bounds__(256) void gemm_bt(
    const u16* __restrict__ A, const u16* __restrict__ Bt, int mode,
    const float* __restrict__ bias0, const float* __restrict__ bias1,
    const float* __restrict__ bias2,
    void* __restrict__ out0, void* __restrict__ out1, void* __restrict__ out2)
{
    __shared__ u16 sh[16896];            // As[2][4096] | Bs[2][4096] | slack
    u16* As = sh;                        // + buf*4096
    u16* Bs = sh + 8192;                 // + buf*4096
    const int t = threadIdx.x, wid = t >> 6, lane = t & 63;
    const int lr = lane & 15, quad = lane >> 4;
    const int m0 = blockIdx.y << 7, n0 = blockIdx.x << 7;
    const int wm = (wid & 1) << 6, wn = (wid >> 1) << 6;
    const int rowA = lane >> 2;
    const int colA = (((lane & 3) - ((lane >> 3) & 3)) & 3) << 3;  // swizzled src
    const int sA = (((lr >> 1) + quad) & 3) << 3;                  // read slot

    f32x4 acc[4][4];
    #pragma unroll
    for (int i = 0; i < 4; ++i)
        #pragma unroll
        for (int j = 0; j < 4; ++j) acc[i][j] = (f32x4){0.f, 0.f, 0.f, 0.f};

    auto stage = [&](int k0s, int buf) {
        #pragma unroll
        for (int i = 0; i < 2; ++i) {
            int ch = wid * 2 + i;
            async_cp16(A  + (size_t)(m0 + ch * 16 + rowA) * DM + k0s + colA,
                       As + buf * 4096 + ch * 16 * 32);
            async_cp16(Bt + (size_t)(n0 + ch * 16 + rowA) * DM + k0s + colA,
                       Bs + buf * 4096 + ch * 16 * 32);
        }
    };

    stage(0, 0);
    __syncthreads();

    for (int k0 = 0; k0 < DM; k0 += 32) {
        const int cur = (k0 >> 5) & 1;
        if (k0 + 32 < DM) stage(k0 + 32, cur ^ 1);

        const u16* Ac = As + cur * 4096;
        const u16* Bc = Bs + cur * 4096;
        bf16x8 af[4], bfr[4];
        #pragma unroll
        for (int mt = 0; mt < 4; ++mt)
            af[mt] = *(const bf16x8*)(Ac + (wm + 16 * mt + lr) * 32 + sA);
        #pragma unroll
        for (int nt = 0; nt < 4; ++nt)
            bfr[nt] = *(const bf16x8*)(Bc + (wn + 16 * nt + lr) * 32 + sA);
        #pragma unroll
        for (int mt = 0; mt < 4; ++mt)
            #pragma unroll
            for (int nt = 0; nt < 4; ++nt)
                acc[mt][nt] = __builtin_amdgcn_mfma_f32_16x16x32_bf16(
                    af[mt], bfr[nt], acc[mt][nt], 0, 0, 0);
        __syncthreads();
    }

    {
        u16* wstrip = sh + wid * 1152;
        const int ngb = n0 + wn;
        const int which = ngb >> 10, nnb = ngb & 1023;
        const int h = nnb >> 6;
        const float* bp = (which == 0) ? bias0 : (which == 1) ? bias1 : bias2;
        const float sc = (which == 0) ? C1 : 1.0f;
        float bias_v[4];
        #pragma unroll
        for (int nt = 0; nt < 4; ++nt) bias_v[nt] = bp[nnb + 16 * nt + lr];

        if (which != 1) {
            // Q (*C1) and V: transposed output [bh][d][s], packed epilogue
            u16* dst = (which == 0) ? (u16*)out0 : (u16*)out2;
            #pragma unroll
            for (int mt = 0; mt < 4; ++mt) {
                #pragma unroll
                for (int nt = 0; nt < 4; ++nt) {
                    uint2 w;
                    w.x = pk2((acc[mt][nt][0] + bias_v[nt]) * sc,
                              (acc[mt][nt][1] + bias_v[nt]) * sc);
                    w.y = pk2((acc[mt][nt][2] + bias_v[nt]) * sc,
                              (acc[mt][nt][3] + bias_v[nt]) * sc);
                    *(uint2*)(wstrip + (16 * nt + lr) * 16 + quad * 4) = w;
                }
                asm volatile("s_waitcnt lgkmcnt(0)" ::: "memory");
                #pragma unroll
                for (int half = 0; half < 2; ++half) {
                    int id = lane + 64 * half;
                    int d = id >> 1, cho = (id & 1) << 3;
                    int m = m0 + wm + 16 * mt + cho;
                    int b = m >> 11, s = m & (SEQ - 1);
                    *(uint4*)(dst + ((size_t)(b * NH + h) * DK + d) * SEQ + s) =
                        *(const uint4*)(wstrip + d * 16 + cho);
                }
                asm volatile("s_waitcnt lgkmcnt(0)" ::: "memory");
            }
        } else {
            // K: [bh][s][d], strip-transpose epilogue
            u16* dst = (u16*)out1;
            #pragma unroll
            for (int mt = 0; mt < 4; ++mt) {
                #pragma unroll
                for (int nt = 0; nt < 4; ++nt)
                    #pragma unroll
                    for (int r = 0; r < 4; ++r)
                        wstrip[(quad * 4 + r) * 72 + 16 * nt + lr] =
                            f2b(acc[mt][nt][r] + bias_v[nt]);
                asm volatile("s_waitcnt lgkmcnt(0)" ::: "memory");
                #pragma unroll
                for (int half = 0; half < 2; ++half) {
                    int id = lane + 64 * half;
                    int mloc = id >> 3, dl = (id & 7) << 3;
                    int m = m0 + wm + 16 * mt + mloc;
                    int b = m >> 11, s = m & (SEQ - 1);
                    *(uint4*)(dst + ((size_t)(b * NH + h) * SEQ + s) * DK + dl) =
                        *(const uint4*)(wstrip + mloc * 72 + dl);
                }
                asm volatile("s_waitcnt lgkmcnt(0)" ::: "memory");
            }
        }
    }
}

// ---------------------------------------------------------------------------
// Final GEMM:  O[4096][1024] f32 = A @ Bt^T + bias.  64x128 tile -> 512
// blocks = 2 blocks/CU.  2-phase loop; 4 waves each own 64x32 (acc[4][2]).
// ---------------------------------------------------------------------------
__global__ __launch_bounds__(256) void gemm_o(
    const u16* __restrict__ A, const u16* __restrict__ Bt,
    const float* __restrict__ bias, float* __restrict__ O)
{
    __shared__ u16 sh[12288];            // As[2][2048] | Bs[2][4096]
    u16* As = sh;                        // + buf*2048
    u16* Bs = sh + 4096;                 // + buf*4096
    const int t = threadIdx.x, wid = t >> 6, lane = t & 63;
    const int lr = lane & 15, quad = lane >> 4;
    const int m0 = blockIdx.y << 6, n0 = blockIdx.x << 7;
    const int wn = wid << 5;
    const int rowA = lane >> 2;
    const int colA = (((lane & 3) - ((lane >> 3) & 3)) & 3) << 3;
    const int sA = (((lr >> 1) + quad) & 3) << 3;

    f32x4 acc[4][2];
    #pragma unroll
    for (int i = 0; i < 4; ++i)
        #pragma unroll
        for (int j = 0; j < 2; ++j) acc[i][j] = (f32x4){0.f, 0.f, 0.f, 0.f};

    auto stage = [&](int k0s, int buf) {
        async_cp16(A + (size_t)(m0 + wid * 16 + rowA) * DM + k0s + colA,
                   As + buf * 2048 + wid * 512);
        async_cp16(Bt + (size_t)(n0 + (2 * wid) * 16 + rowA) * DM + k0s + colA,
                   Bs + buf * 4096 + (2 * wid) * 512);
        async_cp16(Bt + (size_t)(n0 + (2 * wid + 1) * 16 + rowA) * DM + k0s + colA,
                   Bs + buf * 4096 + (2 * wid + 1) * 512);
    };

    stage(0, 0);
    __syncthreads();

    for (int k0 = 0; k0 < DM; k0 += 32) {
        const int cur = (k0 >> 5) & 1;
        if (k0 + 32 < DM) stage(k0 + 32, cur ^ 1);

        const u16* Ac = As + cur * 2048;
        const u16* Bc = Bs + cur * 4096;
        bf16x8 af[4], bfr[2];
        #pragma unroll
        for (int mt = 0; mt < 4; ++mt)
            af[mt] = *(const bf16x8*)(Ac + (16 * mt + lr) * 32 + sA);
        #pragma unroll
        for (int nt = 0; nt < 2; ++nt)
            bfr[nt] = *(const bf16x8*)(Bc + (wn + 16 * nt + lr) * 32 + sA);
        #pragma unroll
        for (int mt = 0; mt < 4; ++mt)
            #pragma unroll
            for (int nt = 0; nt < 2; ++nt)
                acc[mt][nt] = __builtin_amdgcn_mfma_f32_16x16x32_bf16(
                    af[mt], bfr[nt], acc[mt][nt], 0, 0, 0);
        __syncthreads();
    }

    // f32 epilogue via per-wave [16][36] strip -> coalesced float4 stores
    float bias_v[2];
    #pragma unroll
    for (int nt = 0; nt < 2; ++nt) bias_v[nt] = bias[n0 + wn + 16 * nt + lr];
    float* strip = (float*)sh + wid * 576;       // 2304 B per wave
    #pragma unroll
    for (int mt = 0; mt < 4; ++mt) {
        #pragma unroll
        for (int nt = 0; nt < 2; ++nt)
            #pragma unroll
            for (int r = 0; r < 4; ++r)
                strip[(quad * 4 + r) * 36 + 16 * nt + lr] =
                    acc[mt][nt][r] + bias_v[nt];
        asm volatile("s_waitcnt lgkmcnt(0)" ::: "memory");
        #pragma unroll
        for (int rr = 0; rr < 2; ++rr) {
            int id = lane + 64 * rr;
            int row = id >> 3, ch = id & 7;
            float4 v = *(const float4*)(strip + row * 36 + ch * 4);
            *(float4*)(O + (size_t)(m0 + 16 * mt + row) * DM
                         + n0 + wn + ch * 4) = v;
        }
        asm volatile("s_waitcnt lgkmcnt(0)" ::: "memory");
    }
}

// ---------------------------------------------------------------------------
// Flash attention v10 (verbatim R9, HW-verified 50.2us): kv-split, 512
// threads / 8 waves (4 q-waves x 2 kv-groups), 128 q rows; K/V double-
// buffered; in-register softmax (T12).  NO min-waves bound and NO extra
// registers: body sits exactly on the 128-unified-reg / 4-waves-per-SIMD
// knee (R7/R8: forced occupancy = spill; R10: +8 VGPR = occupancy cliff).
// LDS 66560 B -> 2 blocks/CU = 16 waves/CU.
//   Qt (C1-scaled): [bh][d][s]; K: [bh][s][d]; Vt: [bh][64][s] bf16.
// ---------------------------------------------------------------------------
__global__ __launch_bounds__(512) void attn_mfma(
    const u16* __restrict__ Qt, const u16* __restrict__ K,
    const u16* __restrict__ Vt, u16* __restrict__ A)
{
    __shared__ u16 sh[33280];

    const int t = threadIdx.x, wid = t >> 6, lane = t & 63;
    const int l31 = lane & 31, hi = lane >> 5, l7 = lane & 7;
    const int g = wid >> 2, wq = wid & 3;
    const int bx = blockIdx.x;
    const int xcd = bx & 7, within = bx >> 3;      // 0..63
    const int bh  = xcd * 4 + (within >> 4);       // 4 bh per XCD (L2 affinity)
    const int q0  = (within & 15) << 7;            // 128 q rows per block

    const u16* Kb = K  + (size_t)bh * SEQ * DK;
    const u16* Vb = Vt + (size_t)bh * DK * SEQ;

    // Q B-fragments: bQ[s][j] = Qt[d = 16s + 8hi + j][q0 + 32*wq + l31]
    const int qw = q0 + 32 * wq + l31;
    const u16* Qb = Qt + (size_t)bh * DK * SEQ + qw;
    bf16x8 bQ[4];
    #pragma unroll
    for (int s = 0; s < 4; ++s)
        #pragma unroll
        for (int j = 0; j < 8; ++j)
            bQ[s][j] = (short)Qb[(size_t)(16 * s + 8 * hi + j) * SEQ];

    f32x16 O0 = zero16(), O1 = zero16();
    float lr = 0.f;

    // staging: wave w stages rows w*8 + (lane>>3) of each tile; source chunk
    // XOR-swizzled so LDS[row][ck] = G[row][ck ^ (row&7)].
    const int w8row = wid * 8 + (lane >> 3);       // 0..63
    const int scol  = ((l7 ^ (lane >> 3)) << 3);   // row&7 == lane>>3

    const int rA = l31 * 64;                       // row base (u16)
    int cks[4];
    #pragma unroll
    for (int s = 0; s < 4; ++s) cks[s] = ((2 * s + hi) ^ l7) << 3;

    auto stage = [&](int sit, int buf) {
        const int kt = sit << 7;                   // pair start (128 kv)
        u16* kd = sh + (buf << 13) + wid * 512;
        u16* vd = sh + 16384 + (buf << 13) + wid * 512;
        async_cp16(Kb + (size_t)(kt + w8row) * DK + scol,       kd);
        async_cp16(Kb + (size_t)(kt + 64 + w8row) * DK + scol,  kd + 4096);
        async_cp16(Vb + (size_t)w8row * SEQ + kt + scol,        vd);
        async_cp16(Vb + (size_t)w8row * SEQ + kt + 64 + scol,   vd + 4096);
    };

    stage(0, 0);
    __syncthreads();

    for (int sit = 0; sit < SEQ / 128; ++sit) {
        const u16* kbp = sh + ((sit & 1) << 13) + (g << 12) + rA;
        const u16* vbp = sh + 16384 + ((sit & 1) << 13) + (g << 12) + rA;
        if (sit + 1 < SEQ / 128) stage(sit + 1, (sit + 1) & 1);

        // QK^T: Sv[kvt] = sum_s mfma32(Kfrag[kvt][s], Q[s])
        f32x16 Sv[2];
        __builtin_amdgcn_s_setprio(1);
        {
            bf16x8 a;
            Sv[0] = zero16();
            a = *(const bf16x8*)(kbp + cks[0]); Sv[0] = MFMA32(a, bQ[0], Sv[0]);
            a = *(const bf16x8*)(kbp + cks[1]); Sv[0] = MFMA32(a, bQ[1], Sv[0]);
            a = *(const bf16x8*)(kbp + cks[2]); Sv[0] = MFMA32(a, bQ[2], Sv[0]);
            a = *(const bf16x8*)(kbp + cks[3]); Sv[0] = MFMA32(a, bQ[3], Sv[0]);
            Sv[1] = zero16();
            a = *(const bf16x8*)(kbp + 2048 + cks[0]); Sv[1] = MFMA32(a, bQ[0], Sv[1]);
            a = *(const bf16x8*)(kbp + 2048 + cks[1]); Sv[1] = MFMA32(a, bQ[1], Sv[1]);
            a = *(const bf16x8*)(kbp + 2048 + cks[2]); Sv[1] = MFMA32(a, bQ[2], Sv[1]);
            a = *(const bf16x8*)(kbp + 2048 + cks[3]); Sv[1] = MFMA32(a, bQ[3], Sv[1]);
        }
        __builtin_amdgcn_s_setprio(0);

        // in-register softmax + P->bf16 A-fragment rebuild (cvt_pk + permlane)
        unsigned pa[4][4];
        #pragma unroll
        for (int kvt = 0; kvt < 2; ++kvt) {
            float e[16];
            #pragma unroll
            for (int r = 0; r < 16; ++r)
                e[r] = __builtin_amdgcn_exp2f(Sv[kvt][r]);
            lr += (((e[0] + e[1]) + (e[2] + e[3])) +
                   ((e[4] + e[5]) + (e[6] + e[7]))) +
                  (((e[8] + e[9]) + (e[10] + e[11])) +
                   ((e[12] + e[13]) + (e[14] + e[15])));
            unsigned pk8[8];
            #pragma unroll
            for (int i = 0; i < 8; ++i) pk8[i] = pk2(e[2 * i], e[2 * i + 1]);
            #pragma unroll
            for (int ww = 0; ww < 2; ++ww) {
                i32x2 r0 = __builtin_amdgcn_permlane32_swap(
                    (int)pk8[4 * ww + 0], (int)pk8[4 * ww + 2], false, false);
                i32x2 r1 = __builtin_amdgcn_permlane32_swap(
                    (int)pk8[4 * ww + 1], (int)pk8[4 * ww + 3], false, false);
                const int w = 2 * kvt + ww;
                pa[w][0] = (unsigned)r0[0]; pa[w][1] = (unsigned)r1[0];
                pa[w][2] = (unsigned)r0[1]; pa[w][3] = (unsigned)r1[1];
            }
        }

        // PV: O[dt] += sum_w mfma32(PA[w], Vfrag[w][dt])
        __builtin_amdgcn_s_setprio(1);
        #pragma unroll
        for (int w = 0; w < 4; ++w) {
            bf16x8 pw = mk8(pa[w][0], pa[w][1], pa[w][2], pa[w][3]);
            bf16x8 v0 = *(const bf16x8*)(vbp + cks[w]);
            bf16x8 v1 = *(const bf16x8*)(vbp + 2048 + cks[w]);
            O0 = MFMA32(pw, v0, O0);
            O1 = MFMA32(pw, v1, O1);
        }
        __builtin_amdgcn_s_setprio(0);

        __syncthreads();
    }

    // fold lane<->lane+32 (each holds half the kv rows for q=l31)
    lr += __shfl_xor(lr, 32);

    // cross-group reduction: group 1 dumps (O,l) into the retired K region.
    float* lred = (float*)(sh + 32768);
    if (g == 1) {
        float* red = (float*)sh + wq * 2048;       // 8KB per q-wave
        #pragma unroll
        for (int c = 0; c < 4; ++c) {
            float4 v0 = make_float4(O0[4*c], O0[4*c+1], O0[4*c+2], O0[4*c+3]);
            float4 v1 = make_float4(O1[4*c], O1[4*c+1], O1[4*c+2], O1[4*c+3]);
            *(float4*)(red + lane * 32 + ((c ^ l7) << 2))       = v0;
            *(float4*)(red + lane * 32 + (((c + 4) ^ l7) << 2)) = v1;
        }
        if (hi == 0) lred[wq * 32 + l31] = lr;
    }
    __syncthreads();

    if (g == 0) {
        float* red = (float*)sh + wq * 2048;
        #pragma unroll
        for (int c = 0; c < 4; ++c) {
            float4 v0 = *(const float4*)(red + lane * 32 + ((c ^ l7) << 2));
            float4 v1 = *(const float4*)(red + lane * 32 + (((c + 4) ^ l7) << 2));
            O0[4*c] += v0.x; O0[4*c+1] += v0.y; O0[4*c+2] += v0.z; O0[4*c+3] += v0.w;
            O1[4*c] += v1.x; O1[4*c+1] += v1.y; O1[4*c+2] += v1.z; O1[4*c+3] += v1.w;
        }
        lr += lred[wq * 32 + l31];

        // broadcast denominators across the wave's 32 q via per-wave LDS table
        float* lt = (float*)(sh + 33024) + wq * 32;
        lt[l31] = lr;
        asm volatile("s_waitcnt lgkmcnt(0)" ::: "memory");

        const int b = bh >> 4, h = bh & 15;
        u16* Ab = A + (size_t)b * SEQ * DM + h * DK + l31;
        #pragma unroll
        for (int r = 0; r < 16; ++r) {
            const int qr = (r & 3) + 8 * (r >> 2) + 4 * hi;
            const float inv = 1.f / lt[qr];
            u16* dst = Ab + (size_t)(q0 + 32 * wq + qr) * DM;
            dst[0]  = f2b(O0[r] * inv);
            dst[32] = f2b(O1[r] * inv);
        }
    }
}

// ---------------------------------------------------------------------------
extern "C" void kernel_launch(void* const* d_in, const int* in_sizes, int n_in,
                              void* d_out, int out_size, void* d_ws, size_t ws_size,
                              hipStream_t stream)
{
    const float* x  = (const float*)d_in[0];
    const float* Wq = (const float*)d_in[1];
    const float* bq = (const float*)d_in[2];
    const float* Wk = (const float*)d_in[3];
    const float* bk = (const float*)d_in[4];
    const float* Wv = (const float*)d_in[5];
    const float* bv = (const float*)d_in[6];
    const float* Wo = (const float*)d_in[7];
    const float* bo = (const float*)d_in[8];

    const size_t NE = (size_t)M_TOT * DM;        // 4M elems
    u16* xb     = (u16*)d_ws;                    //  8 MB  x bf16
    u16* wt_qkv = xb + NE;                       //  6 MB  [3][1024][1024] (n,k)
    u16* wt_o   = wt_qkv + 3 * (size_t)DM * DM;  //  2 MB
    u16* qt_ws  = wt_o + (size_t)DM * DM;        //  8 MB  [bh][d][s] (C1-scaled)
    u16* k_ws   = qt_ws + NE;                    //  8 MB  [bh][s][d]
    u16* vt_ws  = k_ws + NE;                     //  8 MB  [bh][d][s]
    u16* a_ws   = vt_ws + NE;                    //  8 MB  [4096][1024]

    prep<<<dim3(32, 32, 8), 256, 0, stream>>>(
        x, (uint2*)xb, Wq, Wk, Wv, Wo, wt_qkv);

    gemm_bt<<<dim3(24, 32), 256, 0, stream>>>(
        xb, wt_qkv, 1, bq, bk, bv, qt_ws, k_ws, vt_ws);

    attn_mfma<<<dim3(512), 512, 0, stream>>>(qt_ws, k_ws, vt_ws, a_ws);

    gemm_o<<<dim3(8, 64), 256, 0, stream>>>(a_ws, wt_o, bo, (float*)d_out);
}